// Round 5
// baseline (183.767 us; speedup 1.0000x reference)
//
#include <hip/hip_runtime.h>
#include <math.h>

#define HW2048 (2048ull*2048ull)
typedef float f4 __attribute__((ext_vector_type(4)));
typedef float f2 __attribute__((ext_vector_type(2)));
typedef _Float16 h8 __attribute__((ext_vector_type(8)));   // 16 B

struct BP {
  float P[4][3];   // composed 2-stage bilinear phase weights
  float D2[5];     // d^2 thresholds: L = sum(d2 >= D2[j])
  float cc[5];     // Ts exponent coefs
};

// ---------------- K1: img -> C1 (1024^2) + p2 (512^2) -----------------------
__global__ __launch_bounds__(256) void down12_k(const float* __restrict__ img,
                                                float* __restrict__ C1,
                                                float* __restrict__ p2) {
  int X = blockIdx.x * 16 + threadIdx.x;   // 0..511
  int Y = blockIdx.y * 16 + threadIdx.y;   // 0..511
  int c = blockIdx.z;
  const float* ip = img + (size_t)c * HW2048 + (size_t)(4 * Y) * 2048 + 4 * X;
  f4 r0 = __builtin_nontemporal_load((const f4*)(ip));
  f4 r1 = __builtin_nontemporal_load((const f4*)(ip + 2048));
  f4 r2 = __builtin_nontemporal_load((const f4*)(ip + 4096));
  f4 r3 = __builtin_nontemporal_load((const f4*)(ip + 6144));
  float a00 = 0.25f * (r0.x + r0.y + r1.x + r1.y);
  float a01 = 0.25f * (r0.z + r0.w + r1.z + r1.w);
  float a10 = 0.25f * (r2.x + r2.y + r3.x + r3.y);
  float a11 = 0.25f * (r2.z + r2.w + r3.z + r3.w);
  float* cp = C1 + (size_t)c * 1048576 + (size_t)(2 * Y) * 1024 + 2 * X;
  f2 u; u.x = a00; u.y = a01; *(f2*)cp = u;
  f2 v; v.x = a10; v.y = a11; *(f2*)(cp + 1024) = v;
  p2[((size_t)c * 512 + Y) * 512 + X] = 0.25f * (a00 + a01 + a10 + a11);
}

// ---------------- K2: p2 -> p3 + p4 + p5 ------------------------------------
__global__ __launch_bounds__(256) void down345_k(const float* __restrict__ p2,
                                                 float* __restrict__ p3,
                                                 float* __restrict__ p4,
                                                 float* __restrict__ p5) {
  __shared__ float t4[16][17];
  int tx = threadIdx.x, ty = threadIdx.y;          // (16,16); grid (8,8,3)
  int X = blockIdx.x * 16 + tx;
  int Y = blockIdx.y * 16 + ty;
  int c = blockIdx.z;
  const float* ip = p2 + (size_t)c * 262144 + (size_t)(4 * Y) * 512 + 4 * X;
  f4 r0 = *(const f4*)(ip);
  f4 r1 = *(const f4*)(ip + 512);
  f4 r2 = *(const f4*)(ip + 1024);
  f4 r3 = *(const f4*)(ip + 1536);
  float a00 = 0.25f * (r0.x + r0.y + r1.x + r1.y);
  float a01 = 0.25f * (r0.z + r0.w + r1.z + r1.w);
  float a10 = 0.25f * (r2.x + r2.y + r3.x + r3.y);
  float a11 = 0.25f * (r2.z + r2.w + r3.z + r3.w);
  float* cp = p3 + (size_t)c * 65536 + (size_t)(2 * Y) * 256 + 2 * X;
  f2 u; u.x = a00; u.y = a01; *(f2*)cp = u;
  f2 v; v.x = a10; v.y = a11; *(f2*)(cp + 256) = v;
  float m = 0.25f * (a00 + a01 + a10 + a11);
  t4[ty][tx] = m;
  p4[((size_t)c * 128 + Y) * 128 + X] = m;
  __syncthreads();
  int tid = ty * 16 + tx;
  if (tid < 64) {
    int y = tid >> 3, x = tid & 7;
    float w = 0.25f * (t4[2*y][2*x] + t4[2*y][2*x+1] + t4[2*y+1][2*x] + t4[2*y+1][2*x+1]);
    p5[((size_t)c * 64 + blockIdx.y * 8 + y) * 64 + blockIdx.x * 8 + x] = w;
  }
}

// ---------------- helpers ---------------------------------------------------
__device__ __forceinline__ void up_coords(int o, int n, int& i0, int& i1, float& w0) {
  int m = o >> 1;
  if (o & 1) { i0 = m; i1 = min(m + 1, n - 1); w0 = 0.75f; }
  else       { i0 = max(m - 1, 0); i1 = m;     w0 = 0.25f; }
}

__device__ __forceinline__ float calc_B(float dd, int L, const BP& bp) {
  float d = sqrtf(dd);
  float R = 18.75f / (d + 18.75f);
  float R2 = R * R;
  float cL = (L == 1) ? bp.cc[1] : (L == 2) ? bp.cc[2] : (L == 3) ? bp.cc[3] : bp.cc[4];
  float cm = (L == 1) ? bp.cc[0] : (L == 2) ? bp.cc[1] : (L == 3) ? bp.cc[2] : (L == 4) ? bp.cc[3] : bp.cc[4];
  float tsL = (L >= 5) ? 0.f : __expf(-cL * R2);
  float tsm = __expf(-cm * R2);
  return (0.5f - tsL) / (tsm - tsL + 1e-5f);
}

// ---------------- K3: up-chains (z<9) + classification (z>=9) ---------------
__global__ __launch_bounds__(256) void upclass_k(const float* __restrict__ p3,
                                                 const float* __restrict__ p4,
                                                 const float* __restrict__ p5,
                                                 float* __restrict__ U3,
                                                 float* __restrict__ U4,
                                                 float* __restrict__ U5,
                                                 const float* __restrict__ fixs, int nf,
                                                 unsigned* __restrict__ meta,
                                                 h8* __restrict__ Bbuf, BP bp) {
  __shared__ float a[19][20];
  __shared__ float mid[34][35];
  int z = blockIdx.z;

  if (z >= 9) {   // ---- classification: one 4x2 span per thread ----
    int bid = (z - 9) * 64 + blockIdx.y * 8 + blockIdx.x;
    int sid = bid * 256 + threadIdx.x;       // 0..524287
    int xs = sid & 511, yp = sid >> 9;
    int x0 = xs * 4, y0 = yp * 2;
    float d2[2][4];
#pragma unroll
    for (int j = 0; j < 2; ++j)
#pragma unroll
      for (int i = 0; i < 4; ++i) d2[j][i] = 3.4e38f;
    for (int f = 0; f < nf; ++f) {
      float dx0 = (float)x0 - fixs[2 * f], dy0 = (float)y0 - fixs[2 * f + 1];
#pragma unroll
      for (int j = 0; j < 2; ++j) {
        float dy = dy0 + (float)j, dy2 = dy * dy;
#pragma unroll
        for (int i = 0; i < 4; ++i) {
          float dx = dx0 + (float)i;
          d2[j][i] = fminf(d2[j][i], dx * dx + dy2);
        }
      }
    }
    unsigned m = 0;
    h8 b;
#pragma unroll
    for (int j = 0; j < 2; ++j)
#pragma unroll
      for (int i = 0; i < 4; ++i) {
        float dd = d2[j][i];
        int l = (dd >= bp.D2[0]) + (dd >= bp.D2[1]) + (dd >= bp.D2[2]) +
                (dd >= bp.D2[3]) + (dd >= bp.D2[4]);
        m |= (unsigned)l << (4 * (j * 4 + i));
        float B = (l == 0) ? 0.f : calc_B(dd, l, bp);
        b[j * 4 + i] = (_Float16)B;
      }
    meta[sid] = m;
    Bbuf[sid] = b;
    return;
  }

  int im = z / 3, ch = z - im * 3;   // grid (8,8)
  int X0 = blockIdx.x * 64, Y0 = blockIdx.y * 64;
  int tid = threadIdx.x;
  int bx1 = X0 / 4 - 1, by1 = Y0 / 4 - 1;
  int bx2 = X0 / 2 - 1, by2 = Y0 / 2 - 1;

  if (im == 2) {
    const float* s = p5 + ch * 4096;
    for (int j = tid; j < 18 * 18; j += 256) {
      int r = j / 18, cc = j % 18;
      int gy = min(max(by1 + r, 0), 127), gx = min(max(bx1 + cc, 0), 127);
      int r0, r1, c0, c1; float wy0, wx0;
      up_coords(gy, 64, r0, r1, wy0);
      up_coords(gx, 64, c0, c1, wx0);
      float wy1 = 1.f - wy0, wx1 = 1.f - wx0;
      a[r][cc] = wy0 * (wx0 * s[r0*64+c0] + wx1 * s[r0*64+c1])
               + wy1 * (wx0 * s[r1*64+c0] + wx1 * s[r1*64+c1]);
    }
    __syncthreads();
    for (int j = tid; j < 34 * 34; j += 256) {
      int r = j / 34, cc = j % 34;
      int gy = min(max(by2 + r, 0), 255), gx = min(max(bx2 + cc, 0), 255);
      int r0, r1, c0, c1; float wy0, wx0;
      up_coords(gy, 128, r0, r1, wy0);
      up_coords(gx, 128, c0, c1, wx0);
      float wy1 = 1.f - wy0, wx1 = 1.f - wx0;
      int a0 = r0 - by1, a1 = r1 - by1, b0 = c0 - bx1, b1 = c1 - bx1;
      mid[r][cc] = wy0 * (wx0 * a[a0][b0] + wx1 * a[a0][b1])
                 + wy1 * (wx0 * a[a1][b0] + wx1 * a[a1][b1]);
    }
    __syncthreads();
  } else if (im == 1) {
    const float* s = p4 + ch * 16384;
    for (int j = tid; j < 34 * 34; j += 256) {
      int r = j / 34, cc = j % 34;
      int gy = min(max(by2 + r, 0), 255), gx = min(max(bx2 + cc, 0), 255);
      int r0, r1, c0, c1; float wy0, wx0;
      up_coords(gy, 128, r0, r1, wy0);
      up_coords(gx, 128, c0, c1, wx0);
      float wy1 = 1.f - wy0, wx1 = 1.f - wx0;
      mid[r][cc] = wy0 * (wx0 * s[r0*128+c0] + wx1 * s[r0*128+c1])
                 + wy1 * (wx0 * s[r1*128+c0] + wx1 * s[r1*128+c1]);
    }
    __syncthreads();
  }

  float* dst = (im == 0) ? U3 : (im == 1) ? U4 : U5;
  const float* p3g = p3 + ch * 65536;
  int lx = tid & 63, lyb = tid >> 6;
#pragma unroll 4
  for (int rr = 0; rr < 16; ++rr) {
    int ly = lyb * 16 + rr;
    int x = X0 + lx, y = Y0 + ly;
    int r0, r1, c0, c1; float wy0, wx0;
    up_coords(y, 256, r0, r1, wy0);
    up_coords(x, 256, c0, c1, wx0);
    float wy1 = 1.f - wy0, wx1 = 1.f - wx0;
    float v;
    if (im == 0) {
      v = wy0 * (wx0 * p3g[r0*256+c0] + wx1 * p3g[r0*256+c1])
        + wy1 * (wx0 * p3g[r1*256+c0] + wx1 * p3g[r1*256+c1]);
    } else {
      int a0 = r0 - by2, a1 = r1 - by2, b0 = c0 - bx2, b1 = c1 - bx2;
      v = wy0 * (wx0 * mid[a0][b0] + wx1 * mid[a0][b1])
        + wy1 * (wx0 * mid[a1][b0] + wx1 * mid[a1][b1]);
    }
    dst[((size_t)ch * 512 + y) * 512 + x] = v;
  }
}

// ---------------- samplers ---------------------------------------------------
__device__ __forceinline__ void phase_one(const BP& bp, int ph, float w[3]) {
#pragma unroll
  for (int t = 0; t < 3; ++t)
    w[t] = (ph == 0) ? bp.P[0][t] : (ph == 1) ? bp.P[1][t] : (ph == 2) ? bp.P[2][t] : bp.P[3][t];
}

// 512^2 plane, 8x4 span (x0 mult 8, y0 mult 4): one 3x4 window for 32 px
__device__ __forceinline__ void s2c8(const float* __restrict__ b, int x0, int y0,
                                     const BP& bp, float o[4][8]) {
  int t = x0 >> 2, ky = y0 >> 2;
  int c[4], r[3];
#pragma unroll
  for (int i = 0; i < 4; ++i) c[i] = min(max(t - 1 + i, 0), 511);
#pragma unroll
  for (int j = 0; j < 3; ++j) r[j] = min(max(ky - 1 + j, 0), 511);
  float v[3][4];
#pragma unroll
  for (int j = 0; j < 3; ++j) {
    const float* row = b + r[j] * 512;
    v[j][0] = row[c[0]]; v[j][1] = row[c[1]]; v[j][2] = row[c[2]]; v[j][3] = row[c[3]];
  }
  float rs[4][4];
#pragma unroll
  for (int ry = 0; ry < 4; ++ry)
#pragma unroll
    for (int i = 0; i < 4; ++i)
      rs[ry][i] = bp.P[ry][0] * v[0][i] + bp.P[ry][1] * v[1][i] + bp.P[ry][2] * v[2][i];
#pragma unroll
  for (int ry = 0; ry < 4; ++ry) {
#pragma unroll
    for (int k = 0; k < 4; ++k)
      o[ry][k] = bp.P[k][0] * rs[ry][0] + bp.P[k][1] * rs[ry][1] + bp.P[k][2] * rs[ry][2];
#pragma unroll
    for (int k = 0; k < 4; ++k)
      o[ry][k + 4] = bp.P[k][0] * rs[ry][1] + bp.P[k][1] * rs[ry][2] + bp.P[k][2] * rs[ry][3];
  }
}

// C1 plane (1024^2), 8x4 span: one 4x6 window for 32 px
__device__ __forceinline__ void s1c8(const float* __restrict__ b, int x0, int y0,
                                     float o[4][8]) {
  int q0 = x0 >> 1, qy = y0 >> 1;
  int c[6], r[4];
#pragma unroll
  for (int i = 0; i < 6; ++i) c[i] = min(max(q0 - 1 + i, 0), 1023);
#pragma unroll
  for (int j = 0; j < 4; ++j) r[j] = min(max(qy - 1 + j, 0), 1023);
  float v[4][6];
#pragma unroll
  for (int j = 0; j < 4; ++j) {
    const float* row = b + r[j] * 1024;
#pragma unroll
    for (int i = 0; i < 6; ++i) v[j][i] = row[c[i]];
  }
  float rs[4][6];
#pragma unroll
  for (int i = 0; i < 6; ++i) {
    rs[0][i] = 0.25f * v[0][i] + 0.75f * v[1][i];
    rs[1][i] = 0.75f * v[1][i] + 0.25f * v[2][i];
    rs[2][i] = 0.25f * v[1][i] + 0.75f * v[2][i];
    rs[3][i] = 0.75f * v[2][i] + 0.25f * v[3][i];
  }
#pragma unroll
  for (int ry = 0; ry < 4; ++ry)
#pragma unroll
    for (int k = 0; k < 8; ++k) {
      int j = (k >> 1) + 1;
      o[ry][k] = (k & 1) ? 0.75f * rs[ry][j] + 0.25f * rs[ry][j + 1]
                         : 0.25f * rs[ry][j - 1] + 0.75f * rs[ry][j];
    }
}

// 4x2-span samplers (sub-span fallback)
__device__ __forceinline__ void s2c(const float* __restrict__ b, int x0, int y0,
                                    const BP& bp, float o[2][4]) {
  int t = x0 >> 2, ky = y0 >> 2, yph = y0 & 3;
  int c[3], r[3];
#pragma unroll
  for (int j = 0; j < 3; ++j) {
    c[j] = min(max(t - 1 + j, 0), 511);
    r[j] = min(max(ky - 1 + j, 0), 511);
  }
  float v[3][3];
#pragma unroll
  for (int j = 0; j < 3; ++j) {
    const float* row = b + r[j] * 512;
    v[j][0] = row[c[0]]; v[j][1] = row[c[1]]; v[j][2] = row[c[2]];
  }
  const float* wr0 = bp.P[yph];
  const float* wr1 = bp.P[yph + 1];
  float rv0[3], rv1[3];
#pragma unroll
  for (int i = 0; i < 3; ++i) {
    rv0[i] = wr0[0] * v[0][i] + wr0[1] * v[1][i] + wr0[2] * v[2][i];
    rv1[i] = wr1[0] * v[0][i] + wr1[1] * v[1][i] + wr1[2] * v[2][i];
  }
#pragma unroll
  for (int p = 0; p < 4; ++p) {
    o[0][p] = bp.P[p][0] * rv0[0] + bp.P[p][1] * rv0[1] + bp.P[p][2] * rv0[2];
    o[1][p] = bp.P[p][0] * rv1[0] + bp.P[p][1] * rv1[1] + bp.P[p][2] * rv1[2];
  }
}

__device__ __forceinline__ void s1c(const float* __restrict__ b, int x0, int y0,
                                    float o[2][4]) {
  int q0 = x0 >> 1, qy = y0 >> 1;
  int c[4], r[3];
#pragma unroll
  for (int i = 0; i < 4; ++i) c[i] = min(max(q0 - 1 + i, 0), 1023);
#pragma unroll
  for (int j = 0; j < 3; ++j) r[j] = min(max(qy - 1 + j, 0), 1023);
  float v[3][4];
#pragma unroll
  for (int j = 0; j < 3; ++j) {
    const float* row = b + r[j] * 1024;
    v[j][0] = row[c[0]]; v[j][1] = row[c[1]]; v[j][2] = row[c[2]]; v[j][3] = row[c[3]];
  }
  float rv0[4], rv1[4];
#pragma unroll
  for (int i = 0; i < 4; ++i) {
    rv0[i] = 0.25f * v[0][i] + 0.75f * v[1][i];
    rv1[i] = 0.75f * v[1][i] + 0.25f * v[2][i];
  }
  o[0][0] = 0.25f * rv0[0] + 0.75f * rv0[1];
  o[0][1] = 0.75f * rv0[1] + 0.25f * rv0[2];
  o[0][2] = 0.25f * rv0[1] + 0.75f * rv0[2];
  o[0][3] = 0.75f * rv0[2] + 0.25f * rv0[3];
  o[1][0] = 0.25f * rv1[0] + 0.75f * rv1[1];
  o[1][1] = 0.75f * rv1[1] + 0.25f * rv1[2];
  o[1][2] = 0.25f * rv1[1] + 0.75f * rv1[2];
  o[1][3] = 0.75f * rv1[2] + 0.25f * rv1[3];
}

__device__ float sample_pxc(int level, int x, int y,
                            const float* __restrict__ imgc, const float* __restrict__ C1c,
                            const float* __restrict__ b2, const float* __restrict__ b3,
                            const float* __restrict__ b4, const float* __restrict__ b5,
                            const BP& bp) {
  if (level == 0) return imgc[(size_t)y * 2048 + x];
  if (level == 1) {
    int r0, r1, c0, c1; float wy0, wx0;
    up_coords(y, 1024, r0, r1, wy0);
    up_coords(x, 1024, c0, c1, wx0);
    float wy1 = 1.f - wy0, wx1 = 1.f - wx0;
    return wy0 * (wx0 * C1c[r0 * 1024 + c0] + wx1 * C1c[r0 * 1024 + c1])
         + wy1 * (wx0 * C1c[r1 * 1024 + c0] + wx1 * C1c[r1 * 1024 + c1]);
  }
  const float* buf = (level == 2) ? b2 : (level == 3) ? b3 : (level == 4) ? b4 : b5;
  int ky = y >> 2, kx = x >> 2;
  float wr[3], wc[3];
  phase_one(bp, y & 3, wr);
  phase_one(bp, x & 3, wc);
  float acc = 0.f;
#pragma unroll
  for (int j = 0; j < 3; ++j) {
    int r = min(max(ky - 1 + j, 0), 511);
    const float* row = buf + r * 512;
    float cs = 0.f;
#pragma unroll
    for (int i = 0; i < 3; ++i) {
      int cidx = min(max(kx - 1 + i, 0), 511);
      cs += wc[i] * row[cidx];
    }
    acc += wr[j] * cs;
  }
  return acc;
}

// ---------------- K4: per-channel blend, 8x4 px per thread ------------------
__global__ __launch_bounds__(256) void blendc8_k(
    const float* __restrict__ img, const float* __restrict__ C1,
    const float* __restrict__ B2, const float* __restrict__ B3,
    const float* __restrict__ B4, const float* __restrict__ B5,
    const unsigned* __restrict__ meta, const h8* __restrict__ Bbuf,
    float* __restrict__ out, BP bp) {
  int xs8 = blockIdx.x * 64 + threadIdx.x;   // 0..255
  int yq  = blockIdx.y * 4 + threadIdx.y;    // 0..511
  int ch = blockIdx.z;
  int x0 = xs8 * 8, y0 = yq * 4;
  int xsb = xs8 * 2, ypb = yq * 2;
  unsigned m00 = meta[ypb * 512 + xsb],       m01 = meta[ypb * 512 + xsb + 1];
  unsigned m10 = meta[(ypb + 1) * 512 + xsb], m11 = meta[(ypb + 1) * 512 + xsb + 1];
  size_t ob = (size_t)ch * HW2048 + (size_t)y0 * 2048 + x0;
  const float* imgc = img + (size_t)ch * HW2048;

  float res[4][8];

  if ((m00 | m01 | m10 | m11) == 0u) {          // pure img copy
#pragma unroll
    for (int ry = 0; ry < 4; ++ry) {
      f4 a = *(const f4*)(imgc + (size_t)(y0 + ry) * 2048 + x0);
      f4 b = *(const f4*)(imgc + (size_t)(y0 + ry) * 2048 + x0 + 4);
      __builtin_nontemporal_store(a, (f4*)(out + ob + (size_t)ry * 2048));
      __builtin_nontemporal_store(b, (f4*)(out + ob + (size_t)ry * 2048 + 4));
    }
    return;
  }

  const float* C1c = C1 + (size_t)ch * 1048576;
  const float* b2 = B2 + (size_t)ch * 262144;
  const float* b3 = B3 + (size_t)ch * 262144;
  const float* b4 = B4 + (size_t)ch * 262144;
  const float* b5 = B5 + (size_t)ch * 262144;

  unsigned l0 = m00 & 15u;
  bool uni = (m00 == m01) && (m00 == m10) && (m00 == m11) && (m00 == l0 * 0x11111111u);

  if (uni) {                                     // whole 8x4 same level
    h8 bh00 = Bbuf[ypb * 512 + xsb],       bh01 = Bbuf[ypb * 512 + xsb + 1];
    h8 bh10 = Bbuf[(ypb + 1) * 512 + xsb], bh11 = Bbuf[(ypb + 1) * 512 + xsb + 1];
    float hi[4][8], lo[4][8];
    if (l0 == 1) {
      s1c8(C1c, x0, y0, hi);
#pragma unroll
      for (int ry = 0; ry < 4; ++ry) {
        f4 a = *(const f4*)(imgc + (size_t)(y0 + ry) * 2048 + x0);
        f4 b = *(const f4*)(imgc + (size_t)(y0 + ry) * 2048 + x0 + 4);
        lo[ry][0] = a.x; lo[ry][1] = a.y; lo[ry][2] = a.z; lo[ry][3] = a.w;
        lo[ry][4] = b.x; lo[ry][5] = b.y; lo[ry][6] = b.z; lo[ry][7] = b.w;
      }
    } else if (l0 == 2) {
      s2c8(b2, x0, y0, bp, hi);
      s1c8(C1c, x0, y0, lo);
    } else {
      const float* hb = (l0 == 3) ? b3 : (l0 == 4) ? b4 : b5;
      const float* lb = (l0 == 3) ? b2 : (l0 == 4) ? b3 : b4;
      s2c8(hb, x0, y0, bp, hi);
      s2c8(lb, x0, y0, bp, lo);
    }
#pragma unroll
    for (int ry = 0; ry < 4; ++ry)
#pragma unroll
      for (int k = 0; k < 8; ++k) {
        int e = (ry & 1) * 4 + (k & 3);
        float B = (float)((ry < 2) ? ((k < 4) ? bh00[e] : bh01[e])
                                   : ((k < 4) ? bh10[e] : bh11[e]));
        res[ry][k] = B * lo[ry][k] + (1.f - B) * hi[ry][k];
      }
  } else {
    // per 4x2 sub-span
#pragma unroll
    for (int sy = 0; sy < 2; ++sy)
#pragma unroll
      for (int sx = 0; sx < 2; ++sx) {
        unsigned m = (sy == 0) ? ((sx == 0) ? m00 : m01) : ((sx == 0) ? m10 : m11);
        int sx0 = x0 + sx * 4, sy0 = y0 + sy * 2;
        float sub[2][4];
        if (m == 0u) {
#pragma unroll
          for (int j = 0; j < 2; ++j) {
            f4 v = *(const f4*)(imgc + (size_t)(sy0 + j) * 2048 + sx0);
            sub[j][0] = v.x; sub[j][1] = v.y; sub[j][2] = v.z; sub[j][3] = v.w;
          }
        } else {
          h8 bh = Bbuf[(ypb + sy) * 512 + xsb + sx];
          unsigned sl = m & 15u;
          if (m == sl * 0x11111111u) {
            float shi[2][4], slo[2][4];
            if (sl == 1) {
              s1c(C1c, sx0, sy0, shi);
#pragma unroll
              for (int j = 0; j < 2; ++j) {
                f4 v = *(const f4*)(imgc + (size_t)(sy0 + j) * 2048 + sx0);
                slo[j][0] = v.x; slo[j][1] = v.y; slo[j][2] = v.z; slo[j][3] = v.w;
              }
            } else {
              const float* hb = (sl == 2) ? b2 : (sl == 3) ? b3 : (sl == 4) ? b4 : b5;
              s2c(hb, sx0, sy0, bp, shi);
              if (sl == 2) s1c(C1c, sx0, sy0, slo);
              else {
                const float* lb = (sl == 3) ? b2 : (sl == 4) ? b3 : b4;
                s2c(lb, sx0, sy0, bp, slo);
              }
            }
#pragma unroll
            for (int j = 0; j < 2; ++j)
#pragma unroll
              for (int i = 0; i < 4; ++i) {
                float B = (float)bh[j * 4 + i];
                sub[j][i] = B * slo[j][i] + (1.f - B) * shi[j][i];
              }
          } else {
#pragma unroll
            for (int j = 0; j < 2; ++j)
#pragma unroll
              for (int i = 0; i < 4; ++i) {
                int l = (int)((m >> (4 * (j * 4 + i))) & 15u);
                int px = sx0 + i, py = sy0 + j;
                if (l == 0) {
                  sub[j][i] = imgc[(size_t)py * 2048 + px];
                } else {
                  float B = (float)bh[j * 4 + i];
                  float hi = sample_pxc(l,     px, py, imgc, C1c, b2, b3, b4, b5, bp);
                  float lo = sample_pxc(l - 1, px, py, imgc, C1c, b2, b3, b4, b5, bp);
                  sub[j][i] = B * lo + (1.f - B) * hi;
                }
              }
          }
        }
#pragma unroll
        for (int j = 0; j < 2; ++j)
#pragma unroll
          for (int i = 0; i < 4; ++i)
            res[sy * 2 + j][sx * 4 + i] = sub[j][i];
      }
  }

#pragma unroll
  for (int ry = 0; ry < 4; ++ry) {
    f4 a, b;
    a.x = res[ry][0]; a.y = res[ry][1]; a.z = res[ry][2]; a.w = res[ry][3];
    b.x = res[ry][4]; b.y = res[ry][5]; b.z = res[ry][6]; b.w = res[ry][7];
    __builtin_nontemporal_store(a, (f4*)(out + ob + (size_t)ry * 2048));
    __builtin_nontemporal_store(b, (f4*)(out + ob + (size_t)ry * 2048 + 4));
  }
}

extern "C" void kernel_launch(void* const* d_in, const int* in_sizes, int n_in,
                              void* d_out, int out_size, void* d_ws, size_t ws_size,
                              hipStream_t stream) {
  const float* img  = (const float*)d_in[0];
  const float* fixs = (const float*)d_in[1];
  int nf = in_sizes[1] / 2;
  float* out = (float*)d_out;
  float* ws  = (float*)d_ws;

  BP bp;
  const double sig = 0.248, Kd = 3.0, Pd = 7.5, Ad = 2.5;
  double obv = sqrt(log(2.0) / Kd) * sig;
  for (int j = 0; j < 5; ++j) {
    double om = obv * pow(2.0, 2 - j);
    double Dj = Pd * Ad * (1.0 / om - 1.0);
    bp.D2[j] = (float)(Dj * Dj);
  }
  for (int X = 0; X < 5; ++X)
    bp.cc[X] = (float)(Kd * pow(2.0, 2.0 * (X - 2)) / (sig * sig));
  const float Pt[4][3] = {{0.375f, 0.625f, 0.f},
                          {0.1875f, 0.75f, 0.0625f},
                          {0.0625f, 0.75f, 0.1875f},
                          {0.f, 0.625f, 0.375f}};
  for (int a = 0; a < 4; ++a) for (int t = 0; t < 3; ++t) bp.P[a][t] = Pt[a][t];

  size_t o = 0;
  float* C1 = ws + o; o += 3ull * 1024 * 1024;
  float* p2 = ws + o; o += 3ull * 512 * 512;
  float* p3 = ws + o; o += 3ull * 256 * 256;
  float* p4 = ws + o; o += 3ull * 128 * 128;
  float* p5 = ws + o; o += 3ull * 64 * 64;
  float* U3 = ws + o; o += 3ull * 512 * 512;
  float* U4 = ws + o; o += 3ull * 512 * 512;
  float* U5 = ws + o; o += 3ull * 512 * 512;
  unsigned* meta = (unsigned*)(ws + o); o += 512ull * 1024;
  h8* Bbuf = (h8*)(ws + o); o += 4ull * 512 * 1024;

  down12_k  <<<dim3(32, 32, 3), dim3(16, 16), 0, stream>>>(img, C1, p2);
  down345_k <<<dim3(8, 8, 3),   dim3(16, 16), 0, stream>>>(p2, p3, p4, p5);
  upclass_k <<<dim3(8, 8, 41),  dim3(256),    0, stream>>>(p3, p4, p5, U3, U4, U5,
                                                           fixs, nf, meta, Bbuf, bp);
  blendc8_k <<<dim3(4, 128, 3), dim3(64, 4),  0, stream>>>(img, C1, p2, U3, U4, U5,
                                                           meta, Bbuf, out, bp);
}

// Round 6
// 167.889 us; speedup vs baseline: 1.0946x; 1.0946x over previous
//
#include <hip/hip_runtime.h>
#include <math.h>

#define HW2048 (2048ull*2048ull)
typedef float f4 __attribute__((ext_vector_type(4)));
typedef float f2 __attribute__((ext_vector_type(2)));
typedef _Float16 h8 __attribute__((ext_vector_type(8)));   // 16 B

struct BP {
  float P[4][3];   // composed 2-stage bilinear phase weights
  float D2[5];     // d^2 thresholds: L = sum(d2 >= D2[j])
  float cc[5];     // Ts exponent coefs
};

// ---------------- K1: img -> C1 (1024^2) + p2 (512^2) -----------------------
__global__ __launch_bounds__(256) void down12_k(const float* __restrict__ img,
                                                float* __restrict__ C1,
                                                float* __restrict__ p2) {
  int X = blockIdx.x * 16 + threadIdx.x;   // 0..511
  int Y = blockIdx.y * 16 + threadIdx.y;   // 0..511
  int c = blockIdx.z;
  const float* ip = img + (size_t)c * HW2048 + (size_t)(4 * Y) * 2048 + 4 * X;
  f4 r0 = __builtin_nontemporal_load((const f4*)(ip));
  f4 r1 = __builtin_nontemporal_load((const f4*)(ip + 2048));
  f4 r2 = __builtin_nontemporal_load((const f4*)(ip + 4096));
  f4 r3 = __builtin_nontemporal_load((const f4*)(ip + 6144));
  float a00 = 0.25f * (r0.x + r0.y + r1.x + r1.y);
  float a01 = 0.25f * (r0.z + r0.w + r1.z + r1.w);
  float a10 = 0.25f * (r2.x + r2.y + r3.x + r3.y);
  float a11 = 0.25f * (r2.z + r2.w + r3.z + r3.w);
  float* cp = C1 + (size_t)c * 1048576 + (size_t)(2 * Y) * 1024 + 2 * X;
  f2 u; u.x = a00; u.y = a01; *(f2*)cp = u;
  f2 v; v.x = a10; v.y = a11; *(f2*)(cp + 1024) = v;
  p2[((size_t)c * 512 + Y) * 512 + X] = 0.25f * (a00 + a01 + a10 + a11);
}

// ---------------- K2: p2 -> p3 + p4 + p5 ------------------------------------
__global__ __launch_bounds__(256) void down345_k(const float* __restrict__ p2,
                                                 float* __restrict__ p3,
                                                 float* __restrict__ p4,
                                                 float* __restrict__ p5) {
  __shared__ float t4[16][17];
  int tx = threadIdx.x, ty = threadIdx.y;          // (16,16); grid (8,8,3)
  int X = blockIdx.x * 16 + tx;
  int Y = blockIdx.y * 16 + ty;
  int c = blockIdx.z;
  const float* ip = p2 + (size_t)c * 262144 + (size_t)(4 * Y) * 512 + 4 * X;
  f4 r0 = *(const f4*)(ip);
  f4 r1 = *(const f4*)(ip + 512);
  f4 r2 = *(const f4*)(ip + 1024);
  f4 r3 = *(const f4*)(ip + 1536);
  float a00 = 0.25f * (r0.x + r0.y + r1.x + r1.y);
  float a01 = 0.25f * (r0.z + r0.w + r1.z + r1.w);
  float a10 = 0.25f * (r2.x + r2.y + r3.x + r3.y);
  float a11 = 0.25f * (r2.z + r2.w + r3.z + r3.w);
  float* cp = p3 + (size_t)c * 65536 + (size_t)(2 * Y) * 256 + 2 * X;
  f2 u; u.x = a00; u.y = a01; *(f2*)cp = u;
  f2 v; v.x = a10; v.y = a11; *(f2*)(cp + 256) = v;
  float m = 0.25f * (a00 + a01 + a10 + a11);
  t4[ty][tx] = m;
  p4[((size_t)c * 128 + Y) * 128 + X] = m;
  __syncthreads();
  int tid = ty * 16 + tx;
  if (tid < 64) {
    int y = tid >> 3, x = tid & 7;
    float w = 0.25f * (t4[2*y][2*x] + t4[2*y][2*x+1] + t4[2*y+1][2*x] + t4[2*y+1][2*x+1]);
    p5[((size_t)c * 64 + blockIdx.y * 8 + y) * 64 + blockIdx.x * 8 + x] = w;
  }
}

// ---------------- helpers ---------------------------------------------------
__device__ __forceinline__ void up_coords(int o, int n, int& i0, int& i1, float& w0) {
  int m = o >> 1;
  if (o & 1) { i0 = m; i1 = min(m + 1, n - 1); w0 = 0.75f; }
  else       { i0 = max(m - 1, 0); i1 = m;     w0 = 0.25f; }
}

__device__ __forceinline__ float calc_B(float dd, int L, const BP& bp) {
  float d = sqrtf(dd);
  float R = 18.75f / (d + 18.75f);
  float R2 = R * R;
  float cL = (L == 1) ? bp.cc[1] : (L == 2) ? bp.cc[2] : (L == 3) ? bp.cc[3] : bp.cc[4];
  float cm = (L == 1) ? bp.cc[0] : (L == 2) ? bp.cc[1] : (L == 3) ? bp.cc[2] : (L == 4) ? bp.cc[3] : bp.cc[4];
  float tsL = (L >= 5) ? 0.f : __expf(-cL * R2);
  float tsm = __expf(-cm * R2);
  return (0.5f - tsL) / (tsm - tsL + 1e-5f);
}

// ------- K3: merged up-chains -> pair planes (z<3) + classification (z>=3) --
// P23=(As2src=p2, As3src=U3), P34=(U3,U4), P45=(U4,U5), all 512^2 f2 planes.
__global__ __launch_bounds__(256) void upclass_k(const float* __restrict__ p2,
                                                 const float* __restrict__ p3,
                                                 const float* __restrict__ p4,
                                                 const float* __restrict__ p5,
                                                 f2* __restrict__ P23,
                                                 f2* __restrict__ P34,
                                                 f2* __restrict__ P45,
                                                 const float* __restrict__ fixs, int nf,
                                                 unsigned* __restrict__ meta,
                                                 h8* __restrict__ Bbuf, BP bp) {
  __shared__ float a[18][20];     // 128-level window (U5 chain)
  __shared__ float m3[34][36];    // p3 window (256-level)
  __shared__ float m4[34][36];    // up(p4) at 256-level
  __shared__ float m5[34][36];    // up^2(p5) at 256-level
  int z = blockIdx.z;

  if (z >= 3) {   // ---- classification: one 4x2 span per thread ----
    int bid = (z - 3) * 64 + blockIdx.y * 8 + blockIdx.x;
    int sid = bid * 256 + threadIdx.x;       // 0..524287
    int xs = sid & 511, yp = sid >> 9;
    int x0 = xs * 4, y0 = yp * 2;
    float d2[2][4];
#pragma unroll
    for (int j = 0; j < 2; ++j)
#pragma unroll
      for (int i = 0; i < 4; ++i) d2[j][i] = 3.4e38f;
    for (int f = 0; f < nf; ++f) {
      float dx0 = (float)x0 - fixs[2 * f], dy0 = (float)y0 - fixs[2 * f + 1];
#pragma unroll
      for (int j = 0; j < 2; ++j) {
        float dy = dy0 + (float)j, dy2 = dy * dy;
#pragma unroll
        for (int i = 0; i < 4; ++i) {
          float dx = dx0 + (float)i;
          d2[j][i] = fminf(d2[j][i], dx * dx + dy2);
        }
      }
    }
    unsigned m = 0;
    h8 b;
#pragma unroll
    for (int j = 0; j < 2; ++j)
#pragma unroll
      for (int i = 0; i < 4; ++i) {
        float dd = d2[j][i];
        int l = (dd >= bp.D2[0]) + (dd >= bp.D2[1]) + (dd >= bp.D2[2]) +
                (dd >= bp.D2[3]) + (dd >= bp.D2[4]);
        m |= (unsigned)l << (4 * (j * 4 + i));
        float B = (l == 0) ? 0.f : calc_B(dd, l, bp);
        b[j * 4 + i] = (_Float16)B;
      }
    meta[sid] = m;
    Bbuf[sid] = b;
    return;
  }

  int ch = z;                       // grid (8,8,3) for this branch
  int X0 = blockIdx.x * 64, Y0 = blockIdx.y * 64;
  int tid = threadIdx.x;
  int bx1 = X0 / 4 - 1, by1 = Y0 / 4 - 1;   // 128-level window base
  int bx2 = X0 / 2 - 1, by2 = Y0 / 2 - 1;   // 256-level window base

  // stage A: p5 (64^2) -> a (18x18 @128-level)
  const float* s5 = p5 + ch * 4096;
  for (int j = tid; j < 18 * 18; j += 256) {
    int r = j / 18, cc = j - r * 18;
    int gy = min(max(by1 + r, 0), 127), gx = min(max(bx1 + cc, 0), 127);
    int r0, r1, c0, c1; float wy0, wx0;
    up_coords(gy, 64, r0, r1, wy0);
    up_coords(gx, 64, c0, c1, wx0);
    float wy1 = 1.f - wy0, wx1 = 1.f - wx0;
    a[r][cc] = wy0 * (wx0 * s5[r0*64+c0] + wx1 * s5[r0*64+c1])
             + wy1 * (wx0 * s5[r1*64+c0] + wx1 * s5[r1*64+c1]);
  }
  __syncthreads();
  // stage B: a -> m5; p4 -> m4; p3 -> m3 (all 34x34 @256-level)
  const float* s4 = p4 + ch * 16384;
  const float* s3 = p3 + ch * 65536;
  for (int j = tid; j < 34 * 34; j += 256) {
    int r = j / 34, cc = j - r * 34;
    int gy = min(max(by2 + r, 0), 255), gx = min(max(bx2 + cc, 0), 255);
    int r0, r1, c0, c1; float wy0, wx0;
    up_coords(gy, 128, r0, r1, wy0);
    up_coords(gx, 128, c0, c1, wx0);
    float wy1 = 1.f - wy0, wx1 = 1.f - wx0;
    int a0 = r0 - by1, a1 = r1 - by1, b0 = c0 - bx1, b1 = c1 - bx1;
    m5[r][cc] = wy0 * (wx0 * a[a0][b0] + wx1 * a[a0][b1])
              + wy1 * (wx0 * a[a1][b0] + wx1 * a[a1][b1]);
    m4[r][cc] = wy0 * (wx0 * s4[r0*128+c0] + wx1 * s4[r0*128+c1])
              + wy1 * (wx0 * s4[r1*128+c0] + wx1 * s4[r1*128+c1]);
    m3[r][cc] = s3[gy * 256 + gx];
  }
  __syncthreads();

  const float* p2g = p2 + ch * 262144;
  int lx = tid & 63, lyb = tid >> 6;
#pragma unroll 4
  for (int rr = 0; rr < 16; ++rr) {
    int ly = lyb * 16 + rr;
    int x = X0 + lx, y = Y0 + ly;
    int r0, r1, c0, c1; float wy0, wx0;
    up_coords(y, 256, r0, r1, wy0);
    up_coords(x, 256, c0, c1, wx0);
    float wy1 = 1.f - wy0, wx1 = 1.f - wx0;
    int a0 = r0 - by2, a1 = r1 - by2, b0 = c0 - bx2, b1 = c1 - bx2;
    float u3 = wy0 * (wx0 * m3[a0][b0] + wx1 * m3[a0][b1])
             + wy1 * (wx0 * m3[a1][b0] + wx1 * m3[a1][b1]);
    float u4 = wy0 * (wx0 * m4[a0][b0] + wx1 * m4[a0][b1])
             + wy1 * (wx0 * m4[a1][b0] + wx1 * m4[a1][b1]);
    float u5 = wy0 * (wx0 * m5[a0][b0] + wx1 * m5[a0][b1])
             + wy1 * (wx0 * m5[a1][b0] + wx1 * m5[a1][b1]);
    float p2v = p2g[(size_t)y * 512 + x];
    size_t idx = ((size_t)ch * 512 + y) * 512 + x;
    f2 w;
    w.x = p2v; w.y = u3; P23[idx] = w;
    w.x = u3;  w.y = u4; P34[idx] = w;
    w.x = u4;  w.y = u5; P45[idx] = w;
  }
}

// ---------------- samplers ---------------------------------------------------
__device__ __forceinline__ void phase_one(const BP& bp, int ph, float w[3]) {
#pragma unroll
  for (int t = 0; t < 3; ++t)
    w[t] = (ph == 0) ? bp.P[0][t] : (ph == 1) ? bp.P[1][t] : (ph == 2) ? bp.P[2][t] : bp.P[3][t];
}

// pair-plane (512^2 f2) 4x2-span gather: cx = low level, cy = high level
__device__ __forceinline__ void s2p(const f2* __restrict__ pb, int x0, int y0,
                                    const BP& bp, float cx[2][4], float cy[2][4]) {
  int t = x0 >> 2, ky = y0 >> 2, yph = y0 & 3;
  int c[3], r[3];
#pragma unroll
  for (int j = 0; j < 3; ++j) {
    c[j] = min(max(t - 1 + j, 0), 511);
    r[j] = min(max(ky - 1 + j, 0), 511);
  }
  f2 v[3][3];
#pragma unroll
  for (int j = 0; j < 3; ++j) {
    const f2* row = pb + (size_t)r[j] * 512;
    v[j][0] = row[c[0]]; v[j][1] = row[c[1]]; v[j][2] = row[c[2]];
  }
  const float* wr0 = bp.P[yph];
  const float* wr1 = bp.P[yph + 1];
  f2 rv0[3], rv1[3];
#pragma unroll
  for (int i = 0; i < 3; ++i) {
    rv0[i] = wr0[0] * v[0][i] + wr0[1] * v[1][i] + wr0[2] * v[2][i];
    rv1[i] = wr1[0] * v[0][i] + wr1[1] * v[1][i] + wr1[2] * v[2][i];
  }
#pragma unroll
  for (int p = 0; p < 4; ++p) {
    f2 a0 = bp.P[p][0] * rv0[0] + bp.P[p][1] * rv0[1] + bp.P[p][2] * rv0[2];
    f2 a1 = bp.P[p][0] * rv1[0] + bp.P[p][1] * rv1[1] + bp.P[p][2] * rv1[2];
    cx[0][p] = a0.x; cy[0][p] = a0.y;
    cx[1][p] = a1.x; cy[1][p] = a1.y;
  }
}

// C1 plane (1024^2) 4x2-span single-stage bilinear
__device__ __forceinline__ void s1c(const float* __restrict__ b, int x0, int y0,
                                    float o[2][4]) {
  int q0 = x0 >> 1, qy = y0 >> 1;
  int c[4], r[3];
#pragma unroll
  for (int i = 0; i < 4; ++i) c[i] = min(max(q0 - 1 + i, 0), 1023);
#pragma unroll
  for (int j = 0; j < 3; ++j) r[j] = min(max(qy - 1 + j, 0), 1023);
  float v[3][4];
#pragma unroll
  for (int j = 0; j < 3; ++j) {
    const float* row = b + (size_t)r[j] * 1024;
    v[j][0] = row[c[0]]; v[j][1] = row[c[1]]; v[j][2] = row[c[2]]; v[j][3] = row[c[3]];
  }
  float rv0[4], rv1[4];
#pragma unroll
  for (int i = 0; i < 4; ++i) {
    rv0[i] = 0.25f * v[0][i] + 0.75f * v[1][i];
    rv1[i] = 0.75f * v[1][i] + 0.25f * v[2][i];
  }
  o[0][0] = 0.25f * rv0[0] + 0.75f * rv0[1];
  o[0][1] = 0.75f * rv0[1] + 0.25f * rv0[2];
  o[0][2] = 0.25f * rv0[1] + 0.75f * rv0[2];
  o[0][3] = 0.75f * rv0[2] + 0.25f * rv0[3];
  o[1][0] = 0.25f * rv1[0] + 0.75f * rv1[1];
  o[1][1] = 0.75f * rv1[1] + 0.25f * rv1[2];
  o[1][2] = 0.25f * rv1[1] + 0.75f * rv1[2];
  o[1][3] = 0.75f * rv1[2] + 0.25f * rv1[3];
}

// per-pixel pair gather on a pair plane: returns (low, high)
__device__ __forceinline__ f2 spx_pair(const f2* __restrict__ pb, int x, int y,
                                       const BP& bp) {
  int ky = y >> 2, kx = x >> 2;
  float wr[3], wc[3];
  phase_one(bp, y & 3, wr);
  phase_one(bp, x & 3, wc);
  f2 acc; acc.x = 0.f; acc.y = 0.f;
#pragma unroll
  for (int j = 0; j < 3; ++j) {
    int r = min(max(ky - 1 + j, 0), 511);
    const f2* row = pb + (size_t)r * 512;
    f2 cs; cs.x = 0.f; cs.y = 0.f;
#pragma unroll
    for (int i = 0; i < 3; ++i) {
      int ci = min(max(kx - 1 + i, 0), 511);
      cs += wc[i] * row[ci];
    }
    acc += wr[j] * cs;
  }
  return acc;
}

__device__ __forceinline__ float s1px(const float* __restrict__ C1c, int x, int y) {
  int r0, r1, c0, c1; float wy0, wx0;
  up_coords(y, 1024, r0, r1, wy0);
  up_coords(x, 1024, c0, c1, wx0);
  float wy1 = 1.f - wy0, wx1 = 1.f - wx0;
  return wy0 * (wx0 * C1c[(size_t)r0 * 1024 + c0] + wx1 * C1c[(size_t)r0 * 1024 + c1])
       + wy1 * (wx0 * C1c[(size_t)r1 * 1024 + c0] + wx1 * C1c[(size_t)r1 * 1024 + c1]);
}

// ---------------- K4: per-channel blend, 4x2 px per thread ------------------
__global__ __launch_bounds__(256) void blendc_k(
    const float* __restrict__ img, const float* __restrict__ C1,
    const f2* __restrict__ P23, const f2* __restrict__ P34, const f2* __restrict__ P45,
    const unsigned* __restrict__ meta, const h8* __restrict__ Bbuf,
    float* __restrict__ out, BP bp) {
  int xs = blockIdx.x * 64 + threadIdx.x;   // 0..511
  int yp = blockIdx.y * 4 + threadIdx.y;    // 0..1023
  int ch = blockIdx.z;
  int x0 = xs * 4, y0 = yp * 2;
  int span = yp * 512 + xs;
  size_t ob = (size_t)ch * HW2048 + (size_t)y0 * 2048 + x0;
  const float* imgc = img + (size_t)ch * HW2048;

  unsigned m = meta[span];
  unsigned l0 = m & 15u;
  const f2* P23c = P23 + (size_t)ch * 262144;
  const f2* P34c = P34 + (size_t)ch * 262144;
  const f2* P45c = P45 + (size_t)ch * 262144;
  const float* C1c = C1 + (size_t)ch * 1048576;

  float res[2][4];

  if (m == l0 * 0x11111111u && l0 >= 3u) {
    // dominant path: uniform span, both levels from one pair-plane gather
    const f2* pb = (l0 == 3) ? P23c : (l0 == 4) ? P34c : P45c;
    float lo[2][4], hi[2][4];
    s2p(pb, x0, y0, bp, lo, hi);
    h8 bh = Bbuf[span];
#pragma unroll
    for (int j = 0; j < 2; ++j)
#pragma unroll
      for (int i = 0; i < 4; ++i) {
        float B = (float)bh[j * 4 + i];
        res[j][i] = B * lo[j][i] + (1.f - B) * hi[j][i];
      }
  } else if (m == 0u) {
    f4 v0 = *(const f4*)(imgc + (size_t)y0 * 2048 + x0);
    f4 v1 = *(const f4*)(imgc + (size_t)(y0 + 1) * 2048 + x0);
    __builtin_nontemporal_store(v0, (f4*)(out + ob));
    __builtin_nontemporal_store(v1, (f4*)(out + ob + 2048));
    return;
  } else if (m == l0 * 0x11111111u) {
    // uniform L in {1,2}
    h8 bh = Bbuf[span];
    float hi[2][4], lo[2][4];
    if (l0 == 2) {
      float dummy[2][4];
      s2p(P23c, x0, y0, bp, hi, dummy);   // hi = As[2] = .x component
      s1c(C1c, x0, y0, lo);
    } else {
      s1c(C1c, x0, y0, hi);
#pragma unroll
      for (int j = 0; j < 2; ++j) {
        f4 v = *(const f4*)(imgc + (size_t)(y0 + j) * 2048 + x0);
        lo[j][0] = v.x; lo[j][1] = v.y; lo[j][2] = v.z; lo[j][3] = v.w;
      }
    }
#pragma unroll
    for (int j = 0; j < 2; ++j)
#pragma unroll
      for (int i = 0; i < 4; ++i) {
        float B = (float)bh[j * 4 + i];
        res[j][i] = B * lo[j][i] + (1.f - B) * hi[j][i];
      }
  } else {
    // mixed-L span: per-pixel path
    h8 bh = Bbuf[span];
#pragma unroll
    for (int j = 0; j < 2; ++j)
#pragma unroll
      for (int i = 0; i < 4; ++i) {
        int l = (int)((m >> (4 * (j * 4 + i))) & 15u);
        int px = x0 + i, py = y0 + j;
        if (l == 0) {
          res[j][i] = imgc[(size_t)py * 2048 + px];
        } else {
          float B = (float)bh[j * 4 + i];
          float lo, hi;
          if (l >= 3) {
            const f2* pb = (l == 3) ? P23c : (l == 4) ? P34c : P45c;
            f2 g = spx_pair(pb, px, py, bp);
            lo = g.x; hi = g.y;
          } else if (l == 2) {
            f2 g = spx_pair(P23c, px, py, bp);
            hi = g.x;
            lo = s1px(C1c, px, py);
          } else {
            hi = s1px(C1c, px, py);
            lo = imgc[(size_t)py * 2048 + px];
          }
          res[j][i] = B * lo + (1.f - B) * hi;
        }
      }
  }

  f4 v0, v1;
  v0.x = res[0][0]; v0.y = res[0][1]; v0.z = res[0][2]; v0.w = res[0][3];
  v1.x = res[1][0]; v1.y = res[1][1]; v1.z = res[1][2]; v1.w = res[1][3];
  __builtin_nontemporal_store(v0, (f4*)(out + ob));
  __builtin_nontemporal_store(v1, (f4*)(out + ob + 2048));
}

extern "C" void kernel_launch(void* const* d_in, const int* in_sizes, int n_in,
                              void* d_out, int out_size, void* d_ws, size_t ws_size,
                              hipStream_t stream) {
  const float* img  = (const float*)d_in[0];
  const float* fixs = (const float*)d_in[1];
  int nf = in_sizes[1] / 2;
  float* out = (float*)d_out;
  float* ws  = (float*)d_ws;

  BP bp;
  const double sig = 0.248, Kd = 3.0, Pd = 7.5, Ad = 2.5;
  double obv = sqrt(log(2.0) / Kd) * sig;
  for (int j = 0; j < 5; ++j) {
    double om = obv * pow(2.0, 2 - j);
    double Dj = Pd * Ad * (1.0 / om - 1.0);
    bp.D2[j] = (float)(Dj * Dj);
  }
  for (int X = 0; X < 5; ++X)
    bp.cc[X] = (float)(Kd * pow(2.0, 2.0 * (X - 2)) / (sig * sig));
  const float Pt[4][3] = {{0.375f, 0.625f, 0.f},
                          {0.1875f, 0.75f, 0.0625f},
                          {0.0625f, 0.75f, 0.1875f},
                          {0.f, 0.625f, 0.375f}};
  for (int a = 0; a < 4; ++a) for (int t = 0; t < 3; ++t) bp.P[a][t] = Pt[a][t];

  size_t o = 0;
  float* C1 = ws + o; o += 3ull * 1024 * 1024;
  float* p2 = ws + o; o += 3ull * 512 * 512;
  float* p3 = ws + o; o += 3ull * 256 * 256;
  float* p4 = ws + o; o += 3ull * 128 * 128;
  float* p5 = ws + o; o += 3ull * 64 * 64;
  f2* P23 = (f2*)(ws + o); o += 2ull * 3 * 512 * 512;
  f2* P34 = (f2*)(ws + o); o += 2ull * 3 * 512 * 512;
  f2* P45 = (f2*)(ws + o); o += 2ull * 3 * 512 * 512;
  unsigned* meta = (unsigned*)(ws + o); o += 512ull * 1024;
  h8* Bbuf = (h8*)(ws + o); o += 4ull * 512 * 1024;

  down12_k  <<<dim3(32, 32, 3), dim3(16, 16), 0, stream>>>(img, C1, p2);
  down345_k <<<dim3(8, 8, 3),   dim3(16, 16), 0, stream>>>(p2, p3, p4, p5);
  upclass_k <<<dim3(8, 8, 35),  dim3(256),    0, stream>>>(p2, p3, p4, p5,
                                                           P23, P34, P45,
                                                           fixs, nf, meta, Bbuf, bp);
  blendc_k  <<<dim3(8, 256, 3), dim3(64, 4),  0, stream>>>(img, C1, P23, P34, P45,
                                                           meta, Bbuf, out, bp);
}

// Round 7
// 166.782 us; speedup vs baseline: 1.1018x; 1.0066x over previous
//
#include <hip/hip_runtime.h>
#include <math.h>

#define HW2048 (2048ull*2048ull)
typedef float f4 __attribute__((ext_vector_type(4)));
typedef float f2 __attribute__((ext_vector_type(2)));
typedef _Float16 h8 __attribute__((ext_vector_type(8)));   // 16 B

struct BP {
  float P[4][3];   // composed 2-stage bilinear phase weights
  float D2[5];     // d^2 thresholds: L = sum(d2 >= D2[j])
  float cc[5];     // Ts exponent coefs
};

// ---------------- K1: img -> C1 (1024^2) + p2 (512^2) -----------------------
__global__ __launch_bounds__(256) void down12_k(const float* __restrict__ img,
                                                float* __restrict__ C1,
                                                float* __restrict__ p2) {
  int X = blockIdx.x * 16 + threadIdx.x;   // 0..511
  int Y = blockIdx.y * 16 + threadIdx.y;   // 0..511
  int c = blockIdx.z;
  const float* ip = img + (size_t)c * HW2048 + (size_t)(4 * Y) * 2048 + 4 * X;
  f4 r0 = __builtin_nontemporal_load((const f4*)(ip));
  f4 r1 = __builtin_nontemporal_load((const f4*)(ip + 2048));
  f4 r2 = __builtin_nontemporal_load((const f4*)(ip + 4096));
  f4 r3 = __builtin_nontemporal_load((const f4*)(ip + 6144));
  float a00 = 0.25f * (r0.x + r0.y + r1.x + r1.y);
  float a01 = 0.25f * (r0.z + r0.w + r1.z + r1.w);
  float a10 = 0.25f * (r2.x + r2.y + r3.x + r3.y);
  float a11 = 0.25f * (r2.z + r2.w + r3.z + r3.w);
  float* cp = C1 + (size_t)c * 1048576 + (size_t)(2 * Y) * 1024 + 2 * X;
  f2 u; u.x = a00; u.y = a01; *(f2*)cp = u;
  f2 v; v.x = a10; v.y = a11; *(f2*)(cp + 1024) = v;
  p2[((size_t)c * 512 + Y) * 512 + X] = 0.25f * (a00 + a01 + a10 + a11);
}

// ---------------- K2: p2 -> p3 + p4 + p5 ------------------------------------
__global__ __launch_bounds__(256) void down345_k(const float* __restrict__ p2,
                                                 float* __restrict__ p3,
                                                 float* __restrict__ p4,
                                                 float* __restrict__ p5) {
  __shared__ float t4[16][17];
  int tx = threadIdx.x, ty = threadIdx.y;          // (16,16); grid (8,8,3)
  int X = blockIdx.x * 16 + tx;
  int Y = blockIdx.y * 16 + ty;
  int c = blockIdx.z;
  const float* ip = p2 + (size_t)c * 262144 + (size_t)(4 * Y) * 512 + 4 * X;
  f4 r0 = *(const f4*)(ip);
  f4 r1 = *(const f4*)(ip + 512);
  f4 r2 = *(const f4*)(ip + 1024);
  f4 r3 = *(const f4*)(ip + 1536);
  float a00 = 0.25f * (r0.x + r0.y + r1.x + r1.y);
  float a01 = 0.25f * (r0.z + r0.w + r1.z + r1.w);
  float a10 = 0.25f * (r2.x + r2.y + r3.x + r3.y);
  float a11 = 0.25f * (r2.z + r2.w + r3.z + r3.w);
  float* cp = p3 + (size_t)c * 65536 + (size_t)(2 * Y) * 256 + 2 * X;
  f2 u; u.x = a00; u.y = a01; *(f2*)cp = u;
  f2 v; v.x = a10; v.y = a11; *(f2*)(cp + 256) = v;
  float m = 0.25f * (a00 + a01 + a10 + a11);
  t4[ty][tx] = m;
  p4[((size_t)c * 128 + Y) * 128 + X] = m;
  __syncthreads();
  int tid = ty * 16 + tx;
  if (tid < 64) {
    int y = tid >> 3, x = tid & 7;
    float w = 0.25f * (t4[2*y][2*x] + t4[2*y][2*x+1] + t4[2*y+1][2*x] + t4[2*y+1][2*x+1]);
    p5[((size_t)c * 64 + blockIdx.y * 8 + y) * 64 + blockIdx.x * 8 + x] = w;
  }
}

// ---------------- helpers ---------------------------------------------------
__device__ __forceinline__ void up_coords(int o, int n, int& i0, int& i1, float& w0) {
  int m = o >> 1;
  if (o & 1) { i0 = m; i1 = min(m + 1, n - 1); w0 = 0.75f; }
  else       { i0 = max(m - 1, 0); i1 = m;     w0 = 0.25f; }
}

__device__ __forceinline__ float calc_B(float dd, int L, const BP& bp) {
  float d = sqrtf(dd);
  float R = 18.75f / (d + 18.75f);
  float R2 = R * R;
  float cL = (L == 1) ? bp.cc[1] : (L == 2) ? bp.cc[2] : (L == 3) ? bp.cc[3] : bp.cc[4];
  float cm = (L == 1) ? bp.cc[0] : (L == 2) ? bp.cc[1] : (L == 3) ? bp.cc[2] : (L == 4) ? bp.cc[3] : bp.cc[4];
  float tsL = (L >= 5) ? 0.f : __expf(-cL * R2);
  float tsm = __expf(-cm * R2);
  return (0.5f - tsL) / (tsm - tsL + 1e-5f);
}

// ------- K3: merged up-chains -> pair planes (z<3) + classification (z>=3) --
// P23=(p2, U3), P34=(U3, U4), P45=(U4, U5), all 512^2 f2 planes per channel.
__global__ __launch_bounds__(256) void upclass_k(const float* __restrict__ p2,
                                                 const float* __restrict__ p3,
                                                 const float* __restrict__ p4,
                                                 const float* __restrict__ p5,
                                                 f2* __restrict__ P23,
                                                 f2* __restrict__ P34,
                                                 f2* __restrict__ P45,
                                                 const float* __restrict__ fixs, int nf,
                                                 unsigned* __restrict__ meta,
                                                 h8* __restrict__ Bbuf, BP bp) {
  __shared__ float a[18][20];     // 128-level window (U5 chain)
  __shared__ float m3[34][36];    // p3 window (256-level)
  __shared__ float m4[34][36];    // up(p4) at 256-level
  __shared__ float m5[34][36];    // up^2(p5) at 256-level
  int z = blockIdx.z;

  if (z >= 3) {   // ---- classification: one 4x2 span per thread ----
    int bid = (z - 3) * 64 + blockIdx.y * 8 + blockIdx.x;
    int sid = bid * 256 + threadIdx.x;       // 0..524287
    int xs = sid & 511, yp = sid >> 9;
    int x0 = xs * 4, y0 = yp * 2;
    float d2[2][4];
#pragma unroll
    for (int j = 0; j < 2; ++j)
#pragma unroll
      for (int i = 0; i < 4; ++i) d2[j][i] = 3.4e38f;
    for (int f = 0; f < nf; ++f) {
      float dx0 = (float)x0 - fixs[2 * f], dy0 = (float)y0 - fixs[2 * f + 1];
#pragma unroll
      for (int j = 0; j < 2; ++j) {
        float dy = dy0 + (float)j, dy2 = dy * dy;
#pragma unroll
        for (int i = 0; i < 4; ++i) {
          float dx = dx0 + (float)i;
          d2[j][i] = fminf(d2[j][i], dx * dx + dy2);
        }
      }
    }
    unsigned m = 0;
    h8 b;
#pragma unroll
    for (int j = 0; j < 2; ++j)
#pragma unroll
      for (int i = 0; i < 4; ++i) {
        float dd = d2[j][i];
        int l = (dd >= bp.D2[0]) + (dd >= bp.D2[1]) + (dd >= bp.D2[2]) +
                (dd >= bp.D2[3]) + (dd >= bp.D2[4]);
        m |= (unsigned)l << (4 * (j * 4 + i));
        float B = (l == 0) ? 0.f : calc_B(dd, l, bp);
        b[j * 4 + i] = (_Float16)B;
      }
    meta[sid] = m;
    Bbuf[sid] = b;
    return;
  }

  int ch = z;                       // grid (8,8,3) for this branch
  int X0 = blockIdx.x * 64, Y0 = blockIdx.y * 64;
  int tid = threadIdx.x;
  int bx1 = X0 / 4 - 1, by1 = Y0 / 4 - 1;   // 128-level window base
  int bx2 = X0 / 2 - 1, by2 = Y0 / 2 - 1;   // 256-level window base

  const float* s5 = p5 + ch * 4096;
  for (int j = tid; j < 18 * 18; j += 256) {
    int r = j / 18, cc = j - r * 18;
    int gy = min(max(by1 + r, 0), 127), gx = min(max(bx1 + cc, 0), 127);
    int r0, r1, c0, c1; float wy0, wx0;
    up_coords(gy, 64, r0, r1, wy0);
    up_coords(gx, 64, c0, c1, wx0);
    float wy1 = 1.f - wy0, wx1 = 1.f - wx0;
    a[r][cc] = wy0 * (wx0 * s5[r0*64+c0] + wx1 * s5[r0*64+c1])
             + wy1 * (wx0 * s5[r1*64+c0] + wx1 * s5[r1*64+c1]);
  }
  __syncthreads();
  const float* s4 = p4 + ch * 16384;
  const float* s3 = p3 + ch * 65536;
  for (int j = tid; j < 34 * 34; j += 256) {
    int r = j / 34, cc = j - r * 34;
    int gy = min(max(by2 + r, 0), 255), gx = min(max(bx2 + cc, 0), 255);
    int r0, r1, c0, c1; float wy0, wx0;
    up_coords(gy, 128, r0, r1, wy0);
    up_coords(gx, 128, c0, c1, wx0);
    float wy1 = 1.f - wy0, wx1 = 1.f - wx0;
    int a0 = r0 - by1, a1 = r1 - by1, b0 = c0 - bx1, b1 = c1 - bx1;
    m5[r][cc] = wy0 * (wx0 * a[a0][b0] + wx1 * a[a0][b1])
              + wy1 * (wx0 * a[a1][b0] + wx1 * a[a1][b1]);
    m4[r][cc] = wy0 * (wx0 * s4[r0*128+c0] + wx1 * s4[r0*128+c1])
              + wy1 * (wx0 * s4[r1*128+c0] + wx1 * s4[r1*128+c1]);
    m3[r][cc] = s3[gy * 256 + gx];
  }
  __syncthreads();

  const float* p2g = p2 + ch * 262144;
  int lx = tid & 63, lyb = tid >> 6;
#pragma unroll 4
  for (int rr = 0; rr < 16; ++rr) {
    int ly = lyb * 16 + rr;
    int x = X0 + lx, y = Y0 + ly;
    int r0, r1, c0, c1; float wy0, wx0;
    up_coords(y, 256, r0, r1, wy0);
    up_coords(x, 256, c0, c1, wx0);
    float wy1 = 1.f - wy0, wx1 = 1.f - wx0;
    int a0 = r0 - by2, a1 = r1 - by2, b0 = c0 - bx2, b1 = c1 - bx2;
    float u3 = wy0 * (wx0 * m3[a0][b0] + wx1 * m3[a0][b1])
             + wy1 * (wx0 * m3[a1][b0] + wx1 * m3[a1][b1]);
    float u4 = wy0 * (wx0 * m4[a0][b0] + wx1 * m4[a0][b1])
             + wy1 * (wx0 * m4[a1][b0] + wx1 * m4[a1][b1]);
    float u5 = wy0 * (wx0 * m5[a0][b0] + wx1 * m5[a0][b1])
             + wy1 * (wx0 * m5[a1][b0] + wx1 * m5[a1][b1]);
    float p2v = p2g[(size_t)y * 512 + x];
    size_t idx = ((size_t)ch * 512 + y) * 512 + x;
    f2 w;
    w.x = p2v; w.y = u3; P23[idx] = w;
    w.x = u3;  w.y = u4; P34[idx] = w;
    w.x = u4;  w.y = u5; P45[idx] = w;
  }
}

// ---------------- samplers (global fallback) --------------------------------
__device__ __forceinline__ void phase_one(const BP& bp, int ph, float w[3]) {
#pragma unroll
  for (int t = 0; t < 3; ++t)
    w[t] = (ph == 0) ? bp.P[0][t] : (ph == 1) ? bp.P[1][t] : (ph == 2) ? bp.P[2][t] : bp.P[3][t];
}

__device__ __forceinline__ void s2p(const f2* __restrict__ pb, int x0, int y0,
                                    const BP& bp, float cx[2][4], float cy[2][4]) {
  int t = x0 >> 2, ky = y0 >> 2, yph = y0 & 3;
  int c[3], r[3];
#pragma unroll
  for (int j = 0; j < 3; ++j) {
    c[j] = min(max(t - 1 + j, 0), 511);
    r[j] = min(max(ky - 1 + j, 0), 511);
  }
  f2 v[3][3];
#pragma unroll
  for (int j = 0; j < 3; ++j) {
    const f2* row = pb + (size_t)r[j] * 512;
    v[j][0] = row[c[0]]; v[j][1] = row[c[1]]; v[j][2] = row[c[2]];
  }
  const float* wr0 = bp.P[yph];
  const float* wr1 = bp.P[yph + 1];
  f2 rv0[3], rv1[3];
#pragma unroll
  for (int i = 0; i < 3; ++i) {
    rv0[i] = wr0[0] * v[0][i] + wr0[1] * v[1][i] + wr0[2] * v[2][i];
    rv1[i] = wr1[0] * v[0][i] + wr1[1] * v[1][i] + wr1[2] * v[2][i];
  }
#pragma unroll
  for (int p = 0; p < 4; ++p) {
    f2 a0 = bp.P[p][0] * rv0[0] + bp.P[p][1] * rv0[1] + bp.P[p][2] * rv0[2];
    f2 a1 = bp.P[p][0] * rv1[0] + bp.P[p][1] * rv1[1] + bp.P[p][2] * rv1[2];
    cx[0][p] = a0.x; cy[0][p] = a0.y;
    cx[1][p] = a1.x; cy[1][p] = a1.y;
  }
}

__device__ __forceinline__ void s1c(const float* __restrict__ b, int x0, int y0,
                                    float o[2][4]) {
  int q0 = x0 >> 1, qy = y0 >> 1;
  int c[4], r[3];
#pragma unroll
  for (int i = 0; i < 4; ++i) c[i] = min(max(q0 - 1 + i, 0), 1023);
#pragma unroll
  for (int j = 0; j < 3; ++j) r[j] = min(max(qy - 1 + j, 0), 1023);
  float v[3][4];
#pragma unroll
  for (int j = 0; j < 3; ++j) {
    const float* row = b + (size_t)r[j] * 1024;
    v[j][0] = row[c[0]]; v[j][1] = row[c[1]]; v[j][2] = row[c[2]]; v[j][3] = row[c[3]];
  }
  float rv0[4], rv1[4];
#pragma unroll
  for (int i = 0; i < 4; ++i) {
    rv0[i] = 0.25f * v[0][i] + 0.75f * v[1][i];
    rv1[i] = 0.75f * v[1][i] + 0.25f * v[2][i];
  }
  o[0][0] = 0.25f * rv0[0] + 0.75f * rv0[1];
  o[0][1] = 0.75f * rv0[1] + 0.25f * rv0[2];
  o[0][2] = 0.25f * rv0[1] + 0.75f * rv0[2];
  o[0][3] = 0.75f * rv0[2] + 0.25f * rv0[3];
  o[1][0] = 0.25f * rv1[0] + 0.75f * rv1[1];
  o[1][1] = 0.75f * rv1[1] + 0.25f * rv1[2];
  o[1][2] = 0.25f * rv1[1] + 0.75f * rv1[2];
  o[1][3] = 0.75f * rv1[2] + 0.25f * rv1[3];
}

__device__ __forceinline__ f2 spx_pair(const f2* __restrict__ pb, int x, int y,
                                       const BP& bp) {
  int ky = y >> 2, kx = x >> 2;
  float wr[3], wc[3];
  phase_one(bp, y & 3, wr);
  phase_one(bp, x & 3, wc);
  f2 acc; acc.x = 0.f; acc.y = 0.f;
#pragma unroll
  for (int j = 0; j < 3; ++j) {
    int r = min(max(ky - 1 + j, 0), 511);
    const f2* row = pb + (size_t)r * 512;
    f2 cs; cs.x = 0.f; cs.y = 0.f;
#pragma unroll
    for (int i = 0; i < 3; ++i) {
      int ci = min(max(kx - 1 + i, 0), 511);
      cs += wc[i] * row[ci];
    }
    acc += wr[j] * cs;
  }
  return acc;
}

__device__ __forceinline__ float s1px(const float* __restrict__ C1c, int x, int y) {
  int r0, r1, c0, c1; float wy0, wx0;
  up_coords(y, 1024, r0, r1, wy0);
  up_coords(x, 1024, c0, c1, wx0);
  float wy1 = 1.f - wy0, wx1 = 1.f - wx0;
  return wy0 * (wx0 * C1c[(size_t)r0 * 1024 + c0] + wx1 * C1c[(size_t)r0 * 1024 + c1])
       + wy1 * (wx0 * C1c[(size_t)r1 * 1024 + c0] + wx1 * C1c[(size_t)r1 * 1024 + c1]);
}

// ---------------- K4: per-channel blend, 4x2 px/thread, LDS fast path -------
__global__ __launch_bounds__(256) void blendc_k(
    const float* __restrict__ img, const float* __restrict__ C1,
    const f2* __restrict__ P23, const f2* __restrict__ P34, const f2* __restrict__ P45,
    const unsigned* __restrict__ meta, const h8* __restrict__ Bbuf,
    float* __restrict__ out, BP bp) {
  __shared__ f2 win[4][66];          // 512-level pair-plane window for 256x8 tile
  __shared__ unsigned smn[4], smx[4];
  int tx = threadIdx.x, ty = threadIdx.y;   // (64,4)
  int xs = blockIdx.x * 64 + tx;            // 0..511
  int yp = blockIdx.y * 4 + ty;             // 0..1023
  int ch = blockIdx.z;
  int x0 = xs * 4, y0 = yp * 2;
  int span = yp * 512 + xs;
  size_t ob = (size_t)ch * HW2048 + (size_t)y0 * 2048 + x0;
  const float* imgc = img + (size_t)ch * HW2048;

  unsigned m = meta[span];
  unsigned l0 = m & 15u;

  // ---- block uniformity reduce (wave shuffle + LDS) ----
  unsigned my = (m == l0 * 0x11111111u) ? l0 : 0xFFu;
  unsigned mn = my, mx = my;
#pragma unroll
  for (int off = 32; off >= 1; off >>= 1) {
    mn = min(mn, (unsigned)__shfl_xor((int)mn, off));
    mx = max(mx, (unsigned)__shfl_xor((int)mx, off));
  }
  if (tx == 0) { smn[ty] = mn; smx[ty] = mx; }
  __syncthreads();
  mn = min(min(smn[0], smn[1]), min(smn[2], smn[3]));
  mx = max(max(smx[0], smx[1]), max(smx[2], smx[3]));
  bool fast = (mn == mx) && (mn >= 3u) && (mn <= 5u);   // block-uniform value

  const f2* P23c = P23 + (size_t)ch * 262144;
  const f2* P34c = P34 + (size_t)ch * 262144;
  const f2* P45c = P45 + (size_t)ch * 262144;
  const float* C1c = C1 + (size_t)ch * 1048576;

  float res[2][4];

  if (fast) {
    const f2* pbase = (mn == 3u) ? P23c : (mn == 4u) ? P34c : P45c;
    int rb = blockIdx.y * 2 - 1;     // window row base (512-level)
    int cb = blockIdx.x * 64 - 1;    // window col base
    int tid = ty * 64 + tx;
    for (int i = tid; i < 264; i += 256) {
      int wr = i / 66, wc = i - wr * 66;
      int gr = min(max(rb + wr, 0), 511);
      int gc = min(max(cb + wc, 0), 511);
      win[wr][wc] = pbase[(size_t)gr * 512 + gc];
    }
    h8 bh = Bbuf[span];              // overlap with LDS fill
    __syncthreads();

    int wr0i = ty >> 1;              // window row of ky-1
    f2 v[3][3];
#pragma unroll
    for (int j = 0; j < 3; ++j) {
      v[j][0] = win[wr0i + j][tx];
      v[j][1] = win[wr0i + j][tx + 1];
      v[j][2] = win[wr0i + j][tx + 2];
    }
    int yph = 2 * (ty & 1);
    const float* wr0 = bp.P[yph];
    const float* wr1 = bp.P[yph + 1];
    f2 rv0[3], rv1[3];
#pragma unroll
    for (int i = 0; i < 3; ++i) {
      rv0[i] = wr0[0] * v[0][i] + wr0[1] * v[1][i] + wr0[2] * v[2][i];
      rv1[i] = wr1[0] * v[0][i] + wr1[1] * v[1][i] + wr1[2] * v[2][i];
    }
#pragma unroll
    for (int p = 0; p < 4; ++p) {
      f2 a0 = bp.P[p][0] * rv0[0] + bp.P[p][1] * rv0[1] + bp.P[p][2] * rv0[2];
      f2 a1 = bp.P[p][0] * rv1[0] + bp.P[p][1] * rv1[1] + bp.P[p][2] * rv1[2];
      float B0 = (float)bh[p], B1 = (float)bh[4 + p];
      res[0][p] = B0 * a0.x + (1.f - B0) * a0.y;
      res[1][p] = B1 * a1.x + (1.f - B1) * a1.y;
    }
  } else if (m == 0u) {
    f4 v0 = *(const f4*)(imgc + (size_t)y0 * 2048 + x0);
    f4 v1 = *(const f4*)(imgc + (size_t)(y0 + 1) * 2048 + x0);
    __builtin_nontemporal_store(v0, (f4*)(out + ob));
    __builtin_nontemporal_store(v1, (f4*)(out + ob + 2048));
    return;
  } else if (m == l0 * 0x11111111u && l0 >= 3u) {
    const f2* pb = (l0 == 3) ? P23c : (l0 == 4) ? P34c : P45c;
    float lo[2][4], hi[2][4];
    s2p(pb, x0, y0, bp, lo, hi);
    h8 bh = Bbuf[span];
#pragma unroll
    for (int j = 0; j < 2; ++j)
#pragma unroll
      for (int i = 0; i < 4; ++i) {
        float B = (float)bh[j * 4 + i];
        res[j][i] = B * lo[j][i] + (1.f - B) * hi[j][i];
      }
  } else if (m == l0 * 0x11111111u) {
    h8 bh = Bbuf[span];
    float hi[2][4], lo[2][4];
    if (l0 == 2) {
      float dummy[2][4];
      s2p(P23c, x0, y0, bp, hi, dummy);   // hi = As[2] = .x component
      s1c(C1c, x0, y0, lo);
    } else {
      s1c(C1c, x0, y0, hi);
#pragma unroll
      for (int j = 0; j < 2; ++j) {
        f4 v = *(const f4*)(imgc + (size_t)(y0 + j) * 2048 + x0);
        lo[j][0] = v.x; lo[j][1] = v.y; lo[j][2] = v.z; lo[j][3] = v.w;
      }
    }
#pragma unroll
    for (int j = 0; j < 2; ++j)
#pragma unroll
      for (int i = 0; i < 4; ++i) {
        float B = (float)bh[j * 4 + i];
        res[j][i] = B * lo[j][i] + (1.f - B) * hi[j][i];
      }
  } else {
    h8 bh = Bbuf[span];
#pragma unroll
    for (int j = 0; j < 2; ++j)
#pragma unroll
      for (int i = 0; i < 4; ++i) {
        int l = (int)((m >> (4 * (j * 4 + i))) & 15u);
        int px = x0 + i, py = y0 + j;
        if (l == 0) {
          res[j][i] = imgc[(size_t)py * 2048 + px];
        } else {
          float B = (float)bh[j * 4 + i];
          float lo, hi;
          if (l >= 3) {
            const f2* pb = (l == 3) ? P23c : (l == 4) ? P34c : P45c;
            f2 g = spx_pair(pb, px, py, bp);
            lo = g.x; hi = g.y;
          } else if (l == 2) {
            f2 g = spx_pair(P23c, px, py, bp);
            hi = g.x;
            lo = s1px(C1c, px, py);
          } else {
            hi = s1px(C1c, px, py);
            lo = imgc[(size_t)py * 2048 + px];
          }
          res[j][i] = B * lo + (1.f - B) * hi;
        }
      }
  }

  f4 v0, v1;
  v0.x = res[0][0]; v0.y = res[0][1]; v0.z = res[0][2]; v0.w = res[0][3];
  v1.x = res[1][0]; v1.y = res[1][1]; v1.z = res[1][2]; v1.w = res[1][3];
  __builtin_nontemporal_store(v0, (f4*)(out + ob));
  __builtin_nontemporal_store(v1, (f4*)(out + ob + 2048));
}

extern "C" void kernel_launch(void* const* d_in, const int* in_sizes, int n_in,
                              void* d_out, int out_size, void* d_ws, size_t ws_size,
                              hipStream_t stream) {
  const float* img  = (const float*)d_in[0];
  const float* fixs = (const float*)d_in[1];
  int nf = in_sizes[1] / 2;
  float* out = (float*)d_out;
  float* ws  = (float*)d_ws;

  BP bp;
  const double sig = 0.248, Kd = 3.0, Pd = 7.5, Ad = 2.5;
  double obv = sqrt(log(2.0) / Kd) * sig;
  for (int j = 0; j < 5; ++j) {
    double om = obv * pow(2.0, 2 - j);
    double Dj = Pd * Ad * (1.0 / om - 1.0);
    bp.D2[j] = (float)(Dj * Dj);
  }
  for (int X = 0; X < 5; ++X)
    bp.cc[X] = (float)(Kd * pow(2.0, 2.0 * (X - 2)) / (sig * sig));
  const float Pt[4][3] = {{0.375f, 0.625f, 0.f},
                          {0.1875f, 0.75f, 0.0625f},
                          {0.0625f, 0.75f, 0.1875f},
                          {0.f, 0.625f, 0.375f}};
  for (int a = 0; a < 4; ++a) for (int t = 0; t < 3; ++t) bp.P[a][t] = Pt[a][t];

  size_t o = 0;
  float* C1 = ws + o; o += 3ull * 1024 * 1024;
  float* p2 = ws + o; o += 3ull * 512 * 512;
  float* p3 = ws + o; o += 3ull * 256 * 256;
  float* p4 = ws + o; o += 3ull * 128 * 128;
  float* p5 = ws + o; o += 3ull * 64 * 64;
  f2* P23 = (f2*)(ws + o); o += 2ull * 3 * 512 * 512;
  f2* P34 = (f2*)(ws + o); o += 2ull * 3 * 512 * 512;
  f2* P45 = (f2*)(ws + o); o += 2ull * 3 * 512 * 512;
  unsigned* meta = (unsigned*)(ws + o); o += 512ull * 1024;
  h8* Bbuf = (h8*)(ws + o); o += 4ull * 512 * 1024;

  down12_k  <<<dim3(32, 32, 3), dim3(16, 16), 0, stream>>>(img, C1, p2);
  down345_k <<<dim3(8, 8, 3),   dim3(16, 16), 0, stream>>>(p2, p3, p4, p5);
  upclass_k <<<dim3(8, 8, 35),  dim3(256),    0, stream>>>(p2, p3, p4, p5,
                                                           P23, P34, P45,
                                                           fixs, nf, meta, Bbuf, bp);
  blendc_k  <<<dim3(8, 256, 3), dim3(64, 4),  0, stream>>>(img, C1, P23, P34, P45,
                                                           meta, Bbuf, out, bp);
}